// Round 2
// baseline (1107.283 us; speedup 1.0000x reference)
//
#include <hip/hip_runtime.h>

#define SC 0.70710678118654752440f

__device__ __forceinline__ int refl(int p, int n) {
    if (p < 0) p = -1 - p;
    else if (p >= n) p = 2 * n - 1 - p;
    return p;
}

// scalar c2q band value (slow path): bands lh=(0,5), hl=(2,3), hh=(1,4)
__device__ __forceinline__ float band_val(const float* __restrict__ yh_nc, int H, int W,
                                          int b1, int b2, int p, int w) {
    int i = p >> 1, j = w >> 1;
    size_t o1 = (((size_t)b1 * H + i) * W + j) * 2;
    size_t o2 = (((size_t)b2 * H + i) * W + j) * 2;
    float v;
    if ((p & 1) == 0) {
        int comp = (w & 1);
        v = yh_nc[o1 + comp] + yh_nc[o2 + comp];
    } else {
        if ((w & 1) == 0) v = yh_nc[o1 + 1] - yh_nc[o2 + 1];
        else              v = yh_nc[o2 + 0] - yh_nc[o1 + 0];
    }
    return v;  // NOTE: unscaled (SC applied by caller)
}

// paired band value for cols (2j, 2j+1): one float2 from each of two bands
__device__ __forceinline__ void band_pair(const float* __restrict__ yh_nc, int H, int W,
                                          int b1, int b2, int p, int j,
                                          float& v0, float& v1) {
    int i2 = p >> 1;
    float2 A = *(const float2*)(yh_nc + (((size_t)b1 * H + i2) * W + j) * 2);
    float2 B = *(const float2*)(yh_nc + (((size_t)b2 * H + i2) * W + j) * 2);
    if (p & 1) { v0 = A.y - B.y; v1 = B.x - A.x; }
    else       { v0 = A.x + B.x; v1 = A.y + B.y; }
}

// ---------------------------------------------------------------------------
// Fused _inv_j2plus level: ll (NC,2H,2W) + yh (NC,6,H,W,2) -> out (NC,4H,4W)
// Tile: TI=8 output rows x TJ=128 output cols. Col-pass intermediate y1,y2
// staged in LDS over cols cc0..cc0+71 (raw, reflection resolved at fill).
// ---------------------------------------------------------------------------
#define J2_TI 8
#define J2_TJ 128
#define J2_EXT 72
#define J2_EP 36   // pairs

__global__ __launch_bounds__(256) void j2_fused_kernel(
        const float* __restrict__ ll, const float* __restrict__ yh,
        const float* __restrict__ g0a, const float* __restrict__ g0b,
        const float* __restrict__ g1a, const float* __restrict__ g1b,
        float* __restrict__ out, int H, int W) {
    const int r = 2 * H, c = 2 * W;       // ll dims
    const int R2 = 2 * r;                 // y1/y2 rows = out rows
    const int cOut = 2 * c;               // out cols
    const int tid = threadIdx.x;
    const int nc = blockIdx.y;
    const int colTiles = (4 * W) / J2_TJ;
    const int tile_row = blockIdx.x / colTiles;
    const int tile_col = blockIdx.x % colTiles;
    const int o0 = tile_row * J2_TI;
    const int ow0 = tile_col * J2_TJ;
    const int cc0 = (ow0 >> 1) - 4;

    __shared__ float sY1[J2_TI][J2_EXT];
    __shared__ float sY2[J2_TI][J2_EXT];
    __shared__ float cfl[4][5], cfh[4][5];

    if (tid < 40) {
        int t = tid;
        int which = t / 20;     // 0 -> cfl, 1 -> cfh
        int rem = t % 20;
        int s = rem / 5, k = rem % 5;
        int base = 8 + ((s >> 1) & 1);
        if (which == 0) {
            const float* Fl = (s & 1) ? g0a : g0b;
            cfl[s][k] = Fl[base - 2 * k];
        } else {
            const float* Fh = (s & 1) ? g1a : g1b;
            cfh[s][k] = Fh[base - 2 * k];
        }
    }
    __syncthreads();

    const float* ll_nc = ll + (size_t)nc * r * c;
    const float* yh_nc = yh + (size_t)nc * 6 * H * W * 2;

    // ---- Stage 1: col-pass into LDS
    const int NP = J2_TI * J2_EP;
    for (int pp = tid; pp < NP; pp += 256) {
        int il = pp / J2_EP;
        int u = pp % J2_EP;
        int o = o0 + il;
        int q = o >> 2, s = o & 3;
        int dl = (s & 1) ? -3 : -4;
        int dh = -7 - dl;
        int wr0 = cc0 + 2 * u;
        if (wr0 >= 0 && wr0 + 1 < c) {
            int j = wr0 >> 1;
            float aLLx = 0.f, aLLy = 0.f, a05x = 0.f, a05y = 0.f;
            float a23x = 0.f, a23y = 0.f, a14x = 0.f, a14y = 0.f;
#pragma unroll
            for (int k = 0; k < 5; ++k) {
                float cl = cfl[s][k], ch = cfh[s][k];
                int pl = refl(2 * (q + k) + dl, r);
                int ph = refl(2 * (q + k) + dh, r);
                float2 l2 = *(const float2*)(ll_nc + (size_t)pl * c + wr0);
                aLLx = fmaf(cl, l2.x, aLLx); aLLy = fmaf(cl, l2.y, aLLy);
                float v0, v1;
                band_pair(yh_nc, H, W, 0, 5, ph, j, v0, v1);
                a05x = fmaf(ch, v0, a05x); a05y = fmaf(ch, v1, a05y);
                band_pair(yh_nc, H, W, 2, 3, pl, j, v0, v1);
                a23x = fmaf(cl, v0, a23x); a23y = fmaf(cl, v1, a23y);
                band_pair(yh_nc, H, W, 1, 4, ph, j, v0, v1);
                a14x = fmaf(ch, v0, a14x); a14y = fmaf(ch, v1, a14y);
            }
            sY1[il][2 * u]     = fmaf(SC, a05x, aLLx);
            sY1[il][2 * u + 1] = fmaf(SC, a05y, aLLy);
            sY2[il][2 * u]     = SC * (a23x + a14x);
            sY2[il][2 * u + 1] = SC * (a23y + a14y);
        } else {
            for (int dslot = 0; dslot < 2; ++dslot) {
                int wr = wr0 + dslot;
                int w = refl(wr, c);
                float aLL = 0.f, a05 = 0.f, a23 = 0.f, a14 = 0.f;
                for (int k = 0; k < 5; ++k) {
                    float cl = cfl[s][k], ch = cfh[s][k];
                    int pl = refl(2 * (q + k) + dl, r);
                    int ph = refl(2 * (q + k) + dh, r);
                    aLL = fmaf(cl, ll_nc[(size_t)pl * c + w], aLL);
                    a05 = fmaf(ch, band_val(yh_nc, H, W, 0, 5, ph, w), a05);
                    a23 = fmaf(cl, band_val(yh_nc, H, W, 2, 3, pl, w), a23);
                    a14 = fmaf(ch, band_val(yh_nc, H, W, 1, 4, ph, w), a14);
                }
                sY1[il][2 * u + dslot] = fmaf(SC, a05, aLL);
                sY2[il][2 * u + dslot] = SC * (a23 + a14);
            }
        }
    }
    __syncthreads();

    // ---- Stage 2: row-pass from LDS to out
    float* out_nc = out + (size_t)nc * R2 * cOut;
#pragma unroll
    for (int it = 0; it < (J2_TI * J2_TJ) / 256; ++it) {
        int lin = it * 256 + tid;
        int il = lin / J2_TJ;
        int jj = lin % J2_TJ;
        int sOut = jj & 3;
        int qrel = jj >> 2;
        int dl = (sOut & 1) ? -3 : -4;
        int dh = -7 - dl;
        float a1 = 0.f, a2 = 0.f;
#pragma unroll
        for (int k = 0; k < 5; ++k) {
            a1 = fmaf(cfl[sOut][k], sY1[il][2 * (qrel + k) + dl + 4], a1);
            a2 = fmaf(cfh[sOut][k], sY2[il][2 * (qrel + k) + dh + 4], a2);
        }
        out_nc[(size_t)(o0 + il) * cOut + (ow0 + jj)] = a1 + a2;
    }
}

// ---------------------------------------------------------------------------
// Fused _inv_j1: ll (NC,r,c) + yh (NC,6,H,W,2) -> out (NC,r,c), r=2H,c=2W
// Tile: TH=8 rows x TW=128 cols; LDS slots cover raw cols j0-4 .. j0+131.
// ---------------------------------------------------------------------------
#define J1_TH 8
#define J1_TW 128
#define J1_EXT 136
#define J1_EP 68

__global__ __launch_bounds__(256) void j1_fused_kernel(
        const float* __restrict__ ll, const float* __restrict__ yh,
        const float* __restrict__ g0o, const float* __restrict__ g1o,
        float* __restrict__ out, int H, int W) {
    const int r = 2 * H, c = 2 * W;
    const int tid = threadIdx.x;
    const int nc = blockIdx.y;
    const int colTiles = c / J1_TW;
    const int tile_row = blockIdx.x / colTiles;
    const int tile_col = blockIdx.x % colTiles;
    const int i0 = tile_row * J1_TH;
    const int j0 = tile_col * J1_TW;
    const int cc0 = j0 - 4;

    __shared__ float sY1[J1_TH][J1_EXT];
    __shared__ float sY2[J1_TH][J1_EXT];

    // flipped filters in (uniform) registers
    float g0f[7], g1f[5];
#pragma unroll
    for (int k = 0; k < 7; ++k) g0f[k] = g0o[6 - k];
#pragma unroll
    for (int k = 0; k < 5; ++k) g1f[k] = g1o[4 - k];

    const float* ll_nc = ll + (size_t)nc * r * c;
    const float* yh_nc = yh + (size_t)nc * 6 * H * W * 2;

    // ---- Stage 1: col-pass into LDS
    const int NP = J1_TH * J1_EP;
    for (int pp = tid; pp < NP; pp += 256) {
        int il = pp / J1_EP;
        int u = pp % J1_EP;
        int i = i0 + il;
        int wr0 = cc0 + 2 * u;
        if (wr0 >= 0 && wr0 + 1 < c) {
            int j = wr0 >> 1;
            float aLLx = 0.f, aLLy = 0.f, a05x = 0.f, a05y = 0.f;
            float a23x = 0.f, a23y = 0.f, a14x = 0.f, a14y = 0.f;
#pragma unroll
            for (int k = 0; k < 7; ++k) {
                float c0 = g0f[k];
                int p = refl(i - 3 + k, r);
                float2 l2 = *(const float2*)(ll_nc + (size_t)p * c + wr0);
                aLLx = fmaf(c0, l2.x, aLLx); aLLy = fmaf(c0, l2.y, aLLy);
                float v0, v1;
                band_pair(yh_nc, H, W, 2, 3, p, j, v0, v1);
                a23x = fmaf(c0, v0, a23x); a23y = fmaf(c0, v1, a23y);
            }
#pragma unroll
            for (int k = 0; k < 5; ++k) {
                float c1 = g1f[k];
                int p = refl(i - 2 + k, r);
                float v0, v1;
                band_pair(yh_nc, H, W, 0, 5, p, j, v0, v1);
                a05x = fmaf(c1, v0, a05x); a05y = fmaf(c1, v1, a05y);
                band_pair(yh_nc, H, W, 1, 4, p, j, v0, v1);
                a14x = fmaf(c1, v0, a14x); a14y = fmaf(c1, v1, a14y);
            }
            sY1[il][2 * u]     = fmaf(SC, a05x, aLLx);
            sY1[il][2 * u + 1] = fmaf(SC, a05y, aLLy);
            sY2[il][2 * u]     = SC * (a23x + a14x);
            sY2[il][2 * u + 1] = SC * (a23y + a14y);
        } else {
            for (int dslot = 0; dslot < 2; ++dslot) {
                int wr = wr0 + dslot;
                int w = refl(wr, c);
                float aLL = 0.f, a05 = 0.f, a23 = 0.f, a14 = 0.f;
                for (int k = 0; k < 7; ++k) {
                    int p = refl(i - 3 + k, r);
                    aLL = fmaf(g0f[k], ll_nc[(size_t)p * c + w], aLL);
                    a23 = fmaf(g0f[k], band_val(yh_nc, H, W, 2, 3, p, w), a23);
                }
                for (int k = 0; k < 5; ++k) {
                    int p = refl(i - 2 + k, r);
                    a05 = fmaf(g1f[k], band_val(yh_nc, H, W, 0, 5, p, w), a05);
                    a14 = fmaf(g1f[k], band_val(yh_nc, H, W, 1, 4, p, w), a14);
                }
                sY1[il][2 * u + dslot] = fmaf(SC, a05, aLL);
                sY2[il][2 * u + dslot] = SC * (a23 + a14);
            }
        }
    }
    __syncthreads();

    // ---- Stage 2: row-pass from LDS
    float* out_nc = out + (size_t)nc * r * c;
#pragma unroll
    for (int it = 0; it < (J1_TH * J1_TW) / 256; ++it) {
        int lin = it * 256 + tid;
        int il = lin / J1_TW;
        int jj = lin % J1_TW;
        float a = 0.f;
#pragma unroll
        for (int k = 0; k < 7; ++k)
            a = fmaf(g0f[k], sY1[il][jj + 1 + k], a);
#pragma unroll
        for (int k = 0; k < 5; ++k)
            a = fmaf(g1f[k], sY2[il][jj + 2 + k], a);
        out_nc[(size_t)(i0 + il) * c + (j0 + jj)] = a;
    }
}

extern "C" void kernel_launch(void* const* d_in, const int* in_sizes, int n_in,
                              void* d_out, int out_size, void* d_ws, size_t ws_size,
                              hipStream_t stream) {
    const float* yl  = (const float*)d_in[0];
    const float* yh1 = (const float*)d_in[1];
    const float* yh2 = (const float*)d_in[2];
    const float* yh3 = (const float*)d_in[3];
    const float* g0o = (const float*)d_in[4];
    const float* g1o = (const float*)d_in[5];
    const float* g0a = (const float*)d_in[6];
    const float* g0b = (const float*)d_in[7];
    const float* g1a = (const float*)d_in[8];
    const float* g1b = (const float*)d_in[9];
    float* out = (float*)d_out;

    const int NC = 4 * 64;
    float* llA = (float*)d_ws;                       // (NC,128,128)
    float* llB = llA + (size_t)NC * 128 * 128;       // (NC,256,256)

    dim3 blk(256);

    // ---- Level 3: yl (NC,64,64) + yh3 -> llA (NC,128,128)
    {
        const int H = 32, W = 32;
        int rowTiles = (4 * H) / J2_TI;   // 16
        int colTiles = (4 * W) / J2_TJ;   // 1
        dim3 grid(rowTiles * colTiles, NC);
        j2_fused_kernel<<<grid, blk, 0, stream>>>(yl, yh3, g0a, g0b, g1a, g1b, llA, H, W);
    }
    // ---- Level 2: llA + yh2 -> llB (NC,256,256)
    {
        const int H = 64, W = 64;
        int rowTiles = (4 * H) / J2_TI;   // 32
        int colTiles = (4 * W) / J2_TJ;   // 2
        dim3 grid(rowTiles * colTiles, NC);
        j2_fused_kernel<<<grid, blk, 0, stream>>>(llA, yh2, g0a, g0b, g1a, g1b, llB, H, W);
    }
    // ---- Level 1: llB + yh1 -> out (NC,256,256)
    {
        const int H = 128, W = 128;
        int rowTiles = (2 * H) / J1_TH;   // 32
        int colTiles = (2 * W) / J1_TW;   // 2
        dim3 grid(rowTiles * colTiles, NC);
        j1_fused_kernel<<<grid, blk, 0, stream>>>(llB, yh1, g0o, g1o, out, H, W);
    }
}

// Round 3
// 218.172 us; speedup vs baseline: 5.0753x; 5.0753x over previous
//
#include <hip/hip_runtime.h>

#define SC 0.70710678118654752440f

// branchless half-sample reflection in [0, n): handles one reflection each side
__device__ __forceinline__ int reflFull(int p, int n) {
    int x = max(p, ~p);            // p<0 -> -1-p
    return min(x, 2 * n - 1 - x);  // p>=n -> 2n-1-p
}

// pair-space reflection: NP pairs; reflected pair index + swap flag
__device__ __forceinline__ int pairRefl(int t, int NP, bool& sw) {
    int x = max(t, ~t);
    int tp = min(x, 2 * NP - 1 - x);
    sw = (tp != t);
    return tp;
}

// coefficient index maps (all coefs come from g0b / g1a only):
// cfl[s][k] = g0b[cflIdx], cfh[s][k] = g1a[cfhIdx]
__device__ __forceinline__ constexpr int cflIdx(int s, int k) {
    return (s == 0) ? 8 - 2 * k : (s == 1) ? 1 + 2 * k : (s == 2) ? 9 - 2 * k : 2 * k;
}
__device__ __forceinline__ constexpr int cfhIdx(int s, int k) {
    return (s == 0) ? 1 + 2 * k : (s == 1) ? 8 - 2 * k : (s == 2) ? 2 * k : 9 - 2 * k;
}

struct BandVals { float2 e05, o05, e23, o23, e14, o14; };

// load 6 band float2s at pair-row offset and produce even/odd-slot c2q values
// (unscaled by SC); sw swaps even/odd (reflection parity flip)
__device__ __forceinline__ BandVals loadBands(const float* __restrict__ bp, int HW2,
                                              int boff, bool sw) {
    float2 B0 = *(const float2*)(bp + 0 * HW2 + boff);
    float2 B1 = *(const float2*)(bp + 1 * HW2 + boff);
    float2 B2 = *(const float2*)(bp + 2 * HW2 + boff);
    float2 B3 = *(const float2*)(bp + 3 * HW2 + boff);
    float2 B4 = *(const float2*)(bp + 4 * HW2 + boff);
    float2 B5 = *(const float2*)(bp + 5 * HW2 + boff);
    float2 ve05 = {B0.x + B5.x, B0.y + B5.y}, vo05 = {B0.y - B5.y, B5.x - B0.x};
    float2 ve23 = {B2.x + B3.x, B2.y + B3.y}, vo23 = {B2.y - B3.y, B3.x - B2.x};
    float2 ve14 = {B1.x + B4.x, B1.y + B4.y}, vo14 = {B1.y - B4.y, B4.x - B1.x};
    BandVals r;
    r.e05 = sw ? vo05 : ve05;  r.o05 = sw ? ve05 : vo05;
    r.e23 = sw ? vo23 : ve23;  r.o23 = sw ? ve23 : vo23;
    r.e14 = sw ? vo14 : ve14;  r.o14 = sw ? ve14 : vo14;
    return r;
}

template <int N> struct Log2 { static constexpr int v = 1 + Log2<N / 2>::v; };
template <> struct Log2<1> { static constexpr int v = 0; };

// ---------------------------------------------------------------------------
// j2 col pass: ll (nc,2H,2W) + yh (nc,6,H,W,2) -> y1,y2 (nc,4H,2W)
// thread: (nc, q, u) -> 4 output rows (s=0..3) x col pair (2u,2u+1)
// ---------------------------------------------------------------------------
template <int H, int W>
__global__ __launch_bounds__(256) void j2_col(
        const float* __restrict__ ll, const float* __restrict__ yh,
        const float* __restrict__ g0b, const float* __restrict__ g1a,
        float* __restrict__ y1, float* __restrict__ y2) {
    constexpr int LOGW = Log2<W>::v;
    constexpr int r = 2 * H, C2 = 2 * W, LOGC2 = LOGW + 1, HW2 = H * W * 2;
    int lin = blockIdx.x * 256 + threadIdx.x;
    int u = lin & (W - 1);
    int q = lin >> LOGW;
    int nc = blockIdx.y;
    const float* llp = ll + (size_t)nc * r * C2;
    const float* bp  = yh + (size_t)nc * 6 * HW2;

    float G0[10], SG0[10], SG1[10];
#pragma unroll
    for (int i = 0; i < 10; ++i) {
        G0[i] = g0b[i]; SG0[i] = SC * G0[i]; SG1[i] = SC * g1a[i];
    }
    float2 A1[4], A2[4];
#pragma unroll
    for (int s = 0; s < 4; ++s) { A1[s] = {0.f, 0.f}; A2[s] = {0.f, 0.f}; }

#pragma unroll
    for (int k = 0; k < 5; ++k) {
        int t = q + k - 2;
        int pe = reflFull(2 * t, r);
        int po = reflFull(2 * t + 1, r);
        float2 lle = *(const float2*)(llp + ((pe << LOGC2) + 2 * u));
        float2 llo = *(const float2*)(llp + ((po << LOGC2) + 2 * u));
        bool sw; int tp = pairRefl(t, H, sw);
        int boff = ((tp << LOGW) + u) << 1;
        BandVals B = loadBands(bp, HW2, boff, sw);
#pragma unroll
        for (int s = 0; s < 4; ++s) {
            float2 lv  = (s & 1) ? llo   : lle;
            float2 v05 = (s & 1) ? B.e05 : B.o05;
            float2 v23 = (s & 1) ? B.o23 : B.e23;
            float2 v14 = (s & 1) ? B.e14 : B.o14;
            float cr = G0[cflIdx(s, k)];
            float cs = SG0[cflIdx(s, k)];
            float hs = SG1[cfhIdx(s, k)];
            A1[s].x = fmaf(cr, lv.x, fmaf(hs, v05.x, A1[s].x));
            A1[s].y = fmaf(cr, lv.y, fmaf(hs, v05.y, A1[s].y));
            A2[s].x = fmaf(cs, v23.x, fmaf(hs, v14.x, A2[s].x));
            A2[s].y = fmaf(cs, v23.y, fmaf(hs, v14.y, A2[s].y));
        }
    }
    float* y1p = y1 + (size_t)nc * (4 * H) * C2;
    float* y2p = y2 + (size_t)nc * (4 * H) * C2;
#pragma unroll
    for (int s = 0; s < 4; ++s) {
        int off = (((4 * q + s) << LOGC2) + 2 * u);
        *(float2*)(y1p + off) = A1[s];
        *(float2*)(y2p + off) = A2[s];
    }
}

// ---------------------------------------------------------------------------
// j2 row pass: y1,y2 (nc,4H,2W) -> out (nc,4H,4W)
// thread: (nc, row i, quad q) -> 4 output cols
// ---------------------------------------------------------------------------
template <int H, int W>
__global__ __launch_bounds__(256) void j2_row(
        const float* __restrict__ y1, const float* __restrict__ y2,
        const float* __restrict__ g0b, const float* __restrict__ g1a,
        float* __restrict__ out) {
    constexpr int LOGW = Log2<W>::v;
    constexpr int R2 = 4 * H, C2 = 2 * W, COUT = 4 * W, LOGCOUT = LOGW + 2;
    int lin = blockIdx.x * 256 + threadIdx.x;
    int q = lin & (W - 1);
    int i = lin >> LOGW;
    int nc = blockIdx.y;
    const float* y1r = y1 + (size_t)nc * R2 * C2 + i * C2;
    const float* y2r = y2 + (size_t)nc * R2 * C2 + i * C2;

    float G0[10], G1[10];
#pragma unroll
    for (int kk = 0; kk < 10; ++kk) { G0[kk] = g0b[kk]; G1[kk] = g1a[kk]; }

    float e1[5], o1[5], e2[5], o2[5];
#pragma unroll
    for (int m = 0; m < 5; ++m) {
        int t = q + m - 2;
        bool sw; int tp = pairRefl(t, W, sw);
        float2 f1 = *(const float2*)(y1r + 2 * tp);
        float2 f2 = *(const float2*)(y2r + 2 * tp);
        e1[m] = sw ? f1.y : f1.x;  o1[m] = sw ? f1.x : f1.y;
        e2[m] = sw ? f2.y : f2.x;  o2[m] = sw ? f2.x : f2.y;
    }
    float acc[4];
#pragma unroll
    for (int s = 0; s < 4; ++s) {
        float a = 0.f;
#pragma unroll
        for (int k = 0; k < 5; ++k) {
            float v1 = (s & 1) ? o1[k] : e1[k];
            float v2 = (s & 1) ? e2[k] : o2[k];
            a = fmaf(G0[cflIdx(s, k)], v1, a);
            a = fmaf(G1[cfhIdx(s, k)], v2, a);
        }
        acc[s] = a;
    }
    float* op = out + (size_t)nc * R2 * COUT + ((i << LOGCOUT) + 4 * q);
    *(float4*)op = make_float4(acc[0], acc[1], acc[2], acc[3]);
}

// ---------------------------------------------------------------------------
// j1 col pass: ll (nc,2H,2W) + yh (nc,6,H,W,2) -> y1,y2 (nc,2H,2W)
// thread: (nc, qi, u) -> 4 output rows (4qi..4qi+3) x col pair
// ---------------------------------------------------------------------------
template <int H, int W>
__global__ __launch_bounds__(256) void j1_col(
        const float* __restrict__ ll, const float* __restrict__ yh,
        const float* __restrict__ g0o, const float* __restrict__ g1o,
        float* __restrict__ y1, float* __restrict__ y2) {
    constexpr int LOGW = Log2<W>::v;
    constexpr int r = 2 * H, C2 = 2 * W, LOGC2 = LOGW + 1, HW2 = H * W * 2;
    int lin = blockIdx.x * 256 + threadIdx.x;
    int u = lin & (W - 1);
    int qi = lin >> LOGW;   // [0, r/4)
    int nc = blockIdx.y;
    const float* llp = ll + (size_t)nc * r * C2;
    const float* bp  = yh + (size_t)nc * 6 * HW2;

    float g0f[7], Sg0f[7], Sg1f[5];
#pragma unroll
    for (int k = 0; k < 7; ++k) { g0f[k] = g0o[6 - k]; Sg0f[k] = SC * g0f[k]; }
#pragma unroll
    for (int k = 0; k < 5; ++k) Sg1f[k] = SC * g1o[4 - k];

    float2 A1[4], A2[4];
#pragma unroll
    for (int s = 0; s < 4; ++s) { A1[s] = {0.f, 0.f}; A2[s] = {0.f, 0.f}; }

    // ll contribution (g0, 7 taps, rows 4qi-3 .. 4qi+6)
#pragma unroll
    for (int rr = 0; rr < 10; ++rr) {
        int p = reflFull(4 * qi - 3 + rr, r);
        float2 v = *(const float2*)(llp + ((p << LOGC2) + 2 * u));
#pragma unroll
        for (int di = 0; di < 4; ++di) {
            int k = rr - di;
            if (k >= 0 && k <= 6) {
                A1[di].x = fmaf(g0f[k], v.x, A1[di].x);
                A1[di].y = fmaf(g0f[k], v.y, A1[di].y);
            }
        }
    }
    // band contributions (pair rows 2qi-2 .. 2qi+3)
#pragma unroll
    for (int tr = 0; tr < 6; ++tr) {
        int t = 2 * qi - 2 + tr;
        bool sw; int tp = pairRefl(t, H, sw);
        int boff = ((tp << LOGW) + u) << 1;
        BandVals B = loadBands(bp, HW2, boff, sw);
#pragma unroll
        for (int di = 0; di < 4; ++di) {
            int k1e = 2 * tr - di - 2;   // g1 tap for even slot
            int k1o = k1e + 1;           // g1 tap for odd slot
            int k0e = 2 * tr - di - 1;   // g0 tap for even slot
            int k0o = k0e + 1;           // g0 tap for odd slot
            if (k1e >= 0 && k1e <= 4) {
                A1[di].x = fmaf(Sg1f[k1e], B.e05.x, A1[di].x);
                A1[di].y = fmaf(Sg1f[k1e], B.e05.y, A1[di].y);
                A2[di].x = fmaf(Sg1f[k1e], B.e14.x, A2[di].x);
                A2[di].y = fmaf(Sg1f[k1e], B.e14.y, A2[di].y);
            }
            if (k1o >= 0 && k1o <= 4) {
                A1[di].x = fmaf(Sg1f[k1o], B.o05.x, A1[di].x);
                A1[di].y = fmaf(Sg1f[k1o], B.o05.y, A1[di].y);
                A2[di].x = fmaf(Sg1f[k1o], B.o14.x, A2[di].x);
                A2[di].y = fmaf(Sg1f[k1o], B.o14.y, A2[di].y);
            }
            if (k0e >= 0 && k0e <= 6) {
                A2[di].x = fmaf(Sg0f[k0e], B.e23.x, A2[di].x);
                A2[di].y = fmaf(Sg0f[k0e], B.e23.y, A2[di].y);
            }
            if (k0o >= 0 && k0o <= 6) {
                A2[di].x = fmaf(Sg0f[k0o], B.o23.x, A2[di].x);
                A2[di].y = fmaf(Sg0f[k0o], B.o23.y, A2[di].y);
            }
        }
    }
    float* y1p = y1 + (size_t)nc * r * C2;
    float* y2p = y2 + (size_t)nc * r * C2;
#pragma unroll
    for (int di = 0; di < 4; ++di) {
        int off = (((4 * qi + di) << LOGC2) + 2 * u);
        *(float2*)(y1p + off) = A1[di];
        *(float2*)(y2p + off) = A2[di];
    }
}

// ---------------------------------------------------------------------------
// j1 row pass: y1,y2 (nc,r,c) -> out (nc,r,c); thread -> 4 output cols
// ---------------------------------------------------------------------------
template <int H, int W>
__global__ __launch_bounds__(256) void j1_row(
        const float* __restrict__ y1, const float* __restrict__ y2,
        const float* __restrict__ g0o, const float* __restrict__ g1o,
        float* __restrict__ out) {
    constexpr int LOGW = Log2<W>::v;
    constexpr int r = 2 * H, c = 2 * W, Q = W / 2, LOGQ = LOGW - 1;
    int lin = blockIdx.x * 256 + threadIdx.x;
    int u = lin & (Q - 1);      // quad index
    int i = lin >> LOGQ;        // row
    int nc = blockIdx.y;
    const float* y1r = y1 + (size_t)nc * r * c + i * c;
    const float* y2r = y2 + (size_t)nc * r * c + i * c;

    float g0f[7], g1f[5];
#pragma unroll
    for (int k = 0; k < 7; ++k) g0f[k] = g0o[6 - k];
#pragma unroll
    for (int k = 0; k < 5; ++k) g1f[k] = g1o[4 - k];

    float e1[6], o1[6], e2[6], o2[6];
#pragma unroll
    for (int m = 0; m < 6; ++m) {
        int t = 2 * u - 2 + m;
        bool sw; int tp = pairRefl(t, W, sw);
        float2 f1 = *(const float2*)(y1r + 2 * tp);
        float2 f2 = *(const float2*)(y2r + 2 * tp);
        e1[m] = sw ? f1.y : f1.x;  o1[m] = sw ? f1.x : f1.y;
        e2[m] = sw ? f2.y : f2.x;  o2[m] = sw ? f2.x : f2.y;
    }
    float acc[4];
#pragma unroll
    for (int s = 0; s < 4; ++s) {
        float a = 0.f;
#pragma unroll
        for (int k = 0; k < 7; ++k) {
            int rel = s + k + 1;              // col offset from pair base
            int m = rel >> 1;
            a = fmaf(g0f[k], (rel & 1) ? o1[m] : e1[m], a);
        }
#pragma unroll
        for (int k = 0; k < 5; ++k) {
            int rel = s + k + 2;
            int m = rel >> 1;
            a = fmaf(g1f[k], (rel & 1) ? o2[m] : e2[m], a);
        }
        acc[s] = a;
    }
    float* op = out + (size_t)nc * r * c + i * c + 4 * u;
    *(float4*)op = make_float4(acc[0], acc[1], acc[2], acc[3]);
}

extern "C" void kernel_launch(void* const* d_in, const int* in_sizes, int n_in,
                              void* d_out, int out_size, void* d_ws, size_t ws_size,
                              hipStream_t stream) {
    const float* yl  = (const float*)d_in[0];
    const float* yh1 = (const float*)d_in[1];
    const float* yh2 = (const float*)d_in[2];
    const float* yh3 = (const float*)d_in[3];
    const float* g0o = (const float*)d_in[4];
    const float* g1o = (const float*)d_in[5];
    const float* g0b = (const float*)d_in[7];
    const float* g1a = (const float*)d_in[8];
    float* out = (float*)d_out;

    const int NC = 256;
    char* ws = (char*)d_ws;
    float* llA = (float*)ws;                          // (NC,128,128) 16MB
    float* llB = (float*)(ws + ((size_t)16 << 20));   // (NC,256,256) 64MB
    float* yA  = (float*)(ws + ((size_t)80 << 20));   // y1/y2 region
    size_t rest = (ws_size > ((size_t)80 << 20)) ? ws_size - ((size_t)80 << 20)
                                                 : ((size_t)64 << 20);
    auto chunksFor = [&](size_t yBytes) {
        int c = 1;
        while (c < 16 && 2 * (yBytes / c) > rest) c <<= 1;
        return c;
    };

    // ---- Level 3: yl + yh3 -> llA
    {
        constexpr int H = 32, W = 32;
        size_t yElems = (size_t)NC * 4 * H * 2 * W;
        int chunks = chunksFor(yElems * 4);
        int NCH = NC / chunks;
        float* y1p = yA;
        float* y2p = yA + yElems / chunks;
        for (int nc0 = 0; nc0 < NC; nc0 += NCH) {
            dim3 gc((H * W * NCH > 0 ? (H * W) / 256 : 1), NCH);
            j2_col<H, W><<<dim3((H * W) / 256, NCH), 256, 0, stream>>>(
                yl + (size_t)nc0 * 64 * 64, yh3 + (size_t)nc0 * 6 * H * W * 2,
                g0b, g1a, y1p, y2p);
            j2_row<H, W><<<dim3((4 * H * W) / 256, NCH), 256, 0, stream>>>(
                y1p, y2p, g0b, g1a, llA + (size_t)nc0 * 128 * 128);
        }
    }
    // ---- Level 2: llA + yh2 -> llB
    {
        constexpr int H = 64, W = 64;
        size_t yElems = (size_t)NC * 4 * H * 2 * W;
        int chunks = chunksFor(yElems * 4);
        int NCH = NC / chunks;
        float* y1p = yA;
        float* y2p = yA + yElems / chunks;
        for (int nc0 = 0; nc0 < NC; nc0 += NCH) {
            j2_col<H, W><<<dim3((H * W) / 256, NCH), 256, 0, stream>>>(
                llA + (size_t)nc0 * 128 * 128, yh2 + (size_t)nc0 * 6 * H * W * 2,
                g0b, g1a, y1p, y2p);
            j2_row<H, W><<<dim3((4 * H * W) / 256, NCH), 256, 0, stream>>>(
                y1p, y2p, g0b, g1a, llB + (size_t)nc0 * 256 * 256);
        }
    }
    // ---- Level 1 (j1): llB + yh1 -> out
    {
        constexpr int H = 128, W = 128;
        size_t yElems = (size_t)NC * 2 * H * 2 * W;
        int chunks = chunksFor(yElems * 4);
        int NCH = NC / chunks;
        float* y1p = yA;
        float* y2p = yA + yElems / chunks;
        for (int nc0 = 0; nc0 < NC; nc0 += NCH) {
            j1_col<H, W><<<dim3((2 * H / 4) * W / 256, NCH), 256, 0, stream>>>(
                llB + (size_t)nc0 * 256 * 256, yh1 + (size_t)nc0 * 6 * H * W * 2,
                g0o, g1o, y1p, y2p);
            j1_row<H, W><<<dim3((2 * H) * (W / 2) / 256, NCH), 256, 0, stream>>>(
                y1p, y2p, g0o, g1o, out + (size_t)nc0 * 256 * 256);
        }
    }
}

// Round 4
// 130.008 us; speedup vs baseline: 8.5171x; 1.6781x over previous
//
#include <hip/hip_runtime.h>

#define SC 0.70710678118654752440f

// branchless half-sample reflection in [0, n)
__device__ __forceinline__ int reflFull(int p, int n) {
    int x = max(p, ~p);
    return min(x, 2 * n - 1 - x);
}

// pair-space reflection: NP pairs; reflected pair index + swap flag
__device__ __forceinline__ int pairRefl(int t, int NP, bool& sw) {
    int x = max(t, ~t);
    int tp = min(x, 2 * NP - 1 - x);
    sw = (tp != t);
    return tp;
}

// coefficient index maps: cfl[s][k] = g0b[cflIdx], cfh[s][k] = g1a[cfhIdx]
__device__ __forceinline__ constexpr int cflIdx(int s, int k) {
    return (s == 0) ? 8 - 2 * k : (s == 1) ? 1 + 2 * k : (s == 2) ? 9 - 2 * k : 2 * k;
}
__device__ __forceinline__ constexpr int cfhIdx(int s, int k) {
    return (s == 0) ? 1 + 2 * k : (s == 1) ? 8 - 2 * k : (s == 2) ? 2 * k : 9 - 2 * k;
}

struct BandVals { float2 e05, o05, e23, o23, e14, o14; };

__device__ __forceinline__ BandVals loadBands(const float* __restrict__ bp, int HW2,
                                              int boff, bool sw) {
    float2 B0 = *(const float2*)(bp + 0 * HW2 + boff);
    float2 B1 = *(const float2*)(bp + 1 * HW2 + boff);
    float2 B2 = *(const float2*)(bp + 2 * HW2 + boff);
    float2 B3 = *(const float2*)(bp + 3 * HW2 + boff);
    float2 B4 = *(const float2*)(bp + 4 * HW2 + boff);
    float2 B5 = *(const float2*)(bp + 5 * HW2 + boff);
    float2 ve05 = {B0.x + B5.x, B0.y + B5.y}, vo05 = {B0.y - B5.y, B5.x - B0.x};
    float2 ve23 = {B2.x + B3.x, B2.y + B3.y}, vo23 = {B2.y - B3.y, B3.x - B2.x};
    float2 ve14 = {B1.x + B4.x, B1.y + B4.y}, vo14 = {B1.y - B4.y, B4.x - B1.x};
    BandVals r;
    r.e05 = sw ? vo05 : ve05;  r.o05 = sw ? ve05 : vo05;
    r.e23 = sw ? vo23 : ve23;  r.o23 = sw ? ve23 : vo23;
    r.e14 = sw ? vo14 : ve14;  r.o14 = sw ? ve14 : vo14;
    return r;
}

template <int N> struct Log2 { static constexpr int v = 1 + Log2<N / 2>::v; };
template <> struct Log2<1> { static constexpr int v = 0; };

// ---------------------------------------------------------------------------
// Fused j2 level: ll (nc,2H,2W) + yh (nc,6,H,W,2) -> out (nc,4H,4W)
// Block tile: TI=4*(256/W) output rows x full width 4W. Col stage: 256 tasks
// (qq,u), each = 4 rows x col pair -> LDS. Row stage: full-width, pairRefl
// reads resolve inside LDS (no halo recompute).
// ---------------------------------------------------------------------------
template <int H, int W>
__global__ __launch_bounds__(256) void j2_fused(
        const float* __restrict__ ll, const float* __restrict__ yh,
        const float* __restrict__ g0b, const float* __restrict__ g1a,
        float* __restrict__ out) {
    constexpr int LOGW = Log2<W>::v;
    constexpr int r = 2 * H, C2 = 2 * W, COUT = 4 * W, LOGC2 = LOGW + 1;
    constexpr int HW2 = H * W * 2;
    constexpr int QI = 256 / W;      // quad-rows per tile
    constexpr int TI = 4 * QI;       // tile rows
    __shared__ float sY1[TI][C2];
    __shared__ float sY2[TI][C2];

    const int tid = threadIdx.x;
    const int nc = blockIdx.y;
    const int q0 = blockIdx.x * QI;
    const float* llp = ll + (size_t)nc * r * C2;
    const float* bp  = yh + (size_t)nc * 6 * HW2;

    float G0[10], G1[10];
#pragma unroll
    for (int i = 0; i < 10; ++i) { G0[i] = g0b[i]; G1[i] = g1a[i]; }

    // ---- col stage: task (qq, u)
    {
        int u = tid & (W - 1);
        int qq = tid >> LOGW;
        int q = q0 + qq;
        float2 A1[4], A1b[4], A2[4];
#pragma unroll
        for (int s = 0; s < 4; ++s) {
            A1[s] = {0.f, 0.f}; A1b[s] = {0.f, 0.f}; A2[s] = {0.f, 0.f};
        }
#pragma unroll
        for (int k = 0; k < 5; ++k) {
            int t = q + k - 2;
            int pe = reflFull(2 * t, r);
            int po = reflFull(2 * t + 1, r);
            float2 lle = *(const float2*)(llp + ((pe << LOGC2) + 2 * u));
            float2 llo = *(const float2*)(llp + ((po << LOGC2) + 2 * u));
            bool sw; int tp = pairRefl(t, H, sw);
            int boff = ((tp << LOGW) + u) << 1;
            BandVals B = loadBands(bp, HW2, boff, sw);
#pragma unroll
            for (int s = 0; s < 4; ++s) {
                float2 lv  = (s & 1) ? llo   : lle;
                float2 v05 = (s & 1) ? B.e05 : B.o05;
                float2 v23 = (s & 1) ? B.o23 : B.e23;
                float2 v14 = (s & 1) ? B.e14 : B.o14;
                float c0 = G0[cflIdx(s, k)];
                float c1 = G1[cfhIdx(s, k)];
                A1[s].x  = fmaf(c0, lv.x,  A1[s].x);
                A1[s].y  = fmaf(c0, lv.y,  A1[s].y);
                A1b[s].x = fmaf(c1, v05.x, A1b[s].x);
                A1b[s].y = fmaf(c1, v05.y, A1b[s].y);
                A2[s].x  = fmaf(c0, v23.x, fmaf(c1, v14.x, A2[s].x));
                A2[s].y  = fmaf(c0, v23.y, fmaf(c1, v14.y, A2[s].y));
            }
        }
#pragma unroll
        for (int s = 0; s < 4; ++s) {
            float2 w1 = {fmaf(SC, A1b[s].x, A1[s].x), fmaf(SC, A1b[s].y, A1[s].y)};
            float2 w2 = {SC * A2[s].x, SC * A2[s].y};
            *(float2*)&sY1[4 * qq + s][2 * u] = w1;
            *(float2*)&sY2[4 * qq + s][2 * u] = w2;
        }
    }
    __syncthreads();

    // ---- row stage: full-width, 4 quads per thread
    float* op = out + (size_t)nc * (4 * H) * COUT;
#pragma unroll
    for (int v = 0; v < 4; ++v) {
        int lin = v * 256 + tid;
        int qc = lin & (W - 1);
        int il = lin >> LOGW;
        float e1[5], o1[5], e2[5], o2[5];
#pragma unroll
        for (int m = 0; m < 5; ++m) {
            int t = qc + m - 2;
            bool sw; int tp = pairRefl(t, W, sw);
            float2 f1 = *(const float2*)&sY1[il][2 * tp];
            float2 f2 = *(const float2*)&sY2[il][2 * tp];
            e1[m] = sw ? f1.y : f1.x;  o1[m] = sw ? f1.x : f1.y;
            e2[m] = sw ? f2.y : f2.x;  o2[m] = sw ? f2.x : f2.y;
        }
        float acc[4];
#pragma unroll
        for (int s = 0; s < 4; ++s) {
            float a = 0.f;
#pragma unroll
            for (int k = 0; k < 5; ++k) {
                float v1 = (s & 1) ? o1[k] : e1[k];
                float v2 = (s & 1) ? e2[k] : o2[k];
                a = fmaf(G0[cflIdx(s, k)], v1, a);
                a = fmaf(G1[cfhIdx(s, k)], v2, a);
            }
            acc[s] = a;
        }
        int grow = 4 * q0 + il;
        *(float4*)(op + (size_t)grow * COUT + 4 * qc) =
            make_float4(acc[0], acc[1], acc[2], acc[3]);
    }
}

// ---------------------------------------------------------------------------
// Fused j1: ll (nc,r,c) + yh (nc,6,H,W,2) -> out (nc,r,c), r=2H, c=2W
// Tile: TI=8 rows x full width c=256. Col stage 256 tasks (qq,u); row stage
// 2 quads/thread.
// ---------------------------------------------------------------------------
template <int H, int W>
__global__ __launch_bounds__(256) void j1_fused(
        const float* __restrict__ ll, const float* __restrict__ yh,
        const float* __restrict__ g0o, const float* __restrict__ g1o,
        float* __restrict__ out) {
    constexpr int LOGW = Log2<W>::v;
    constexpr int r = 2 * H, c = 2 * W, LOGC2 = LOGW + 1;
    constexpr int HW2 = H * W * 2;
    constexpr int QI = 256 / W;      // quad-row groups per tile (=2)
    constexpr int TI = 4 * QI;       // tile rows (=8)
    __shared__ float sY1[TI][c];
    __shared__ float sY2[TI][c];

    const int tid = threadIdx.x;
    const int nc = blockIdx.y;
    const int qi0 = blockIdx.x * QI;
    const float* llp = ll + (size_t)nc * r * c;
    const float* bp  = yh + (size_t)nc * 6 * HW2;

    float g0f[7], g1f[5];
#pragma unroll
    for (int k = 0; k < 7; ++k) g0f[k] = g0o[6 - k];
#pragma unroll
    for (int k = 0; k < 5; ++k) g1f[k] = g1o[4 - k];

    // ---- col stage
    {
        int u = tid & (W - 1);
        int qq = tid >> LOGW;
        int qi = qi0 + qq;
        float2 A1[4], A1b[4], A2[4];
#pragma unroll
        for (int s = 0; s < 4; ++s) {
            A1[s] = {0.f, 0.f}; A1b[s] = {0.f, 0.f}; A2[s] = {0.f, 0.f};
        }
        // ll contribution (g0, rows 4qi-3 .. 4qi+6)
#pragma unroll
        for (int rr = 0; rr < 10; ++rr) {
            int p = reflFull(4 * qi - 3 + rr, r);
            float2 v = *(const float2*)(llp + ((p << LOGC2) + 2 * u));
#pragma unroll
            for (int di = 0; di < 4; ++di) {
                int k = rr - di;
                if (k >= 0 && k <= 6) {
                    A1[di].x = fmaf(g0f[k], v.x, A1[di].x);
                    A1[di].y = fmaf(g0f[k], v.y, A1[di].y);
                }
            }
        }
        // band contributions (pair rows 2qi-2 .. 2qi+3)
#pragma unroll
        for (int tr = 0; tr < 6; ++tr) {
            int t = 2 * qi - 2 + tr;
            bool sw; int tp = pairRefl(t, H, sw);
            int boff = ((tp << LOGW) + u) << 1;
            BandVals B = loadBands(bp, HW2, boff, sw);
#pragma unroll
            for (int di = 0; di < 4; ++di) {
                int k1e = 2 * tr - di - 2;
                int k1o = k1e + 1;
                int k0e = 2 * tr - di - 1;
                int k0o = k0e + 1;
                if (k1e >= 0 && k1e <= 4) {
                    A1b[di].x = fmaf(g1f[k1e], B.e05.x, A1b[di].x);
                    A1b[di].y = fmaf(g1f[k1e], B.e05.y, A1b[di].y);
                    A2[di].x  = fmaf(g1f[k1e], B.e14.x, A2[di].x);
                    A2[di].y  = fmaf(g1f[k1e], B.e14.y, A2[di].y);
                }
                if (k1o >= 0 && k1o <= 4) {
                    A1b[di].x = fmaf(g1f[k1o], B.o05.x, A1b[di].x);
                    A1b[di].y = fmaf(g1f[k1o], B.o05.y, A1b[di].y);
                    A2[di].x  = fmaf(g1f[k1o], B.o14.x, A2[di].x);
                    A2[di].y  = fmaf(g1f[k1o], B.o14.y, A2[di].y);
                }
                if (k0e >= 0 && k0e <= 6) {
                    A2[di].x = fmaf(g0f[k0e], B.e23.x, A2[di].x);
                    A2[di].y = fmaf(g0f[k0e], B.e23.y, A2[di].y);
                }
                if (k0o >= 0 && k0o <= 6) {
                    A2[di].x = fmaf(g0f[k0o], B.o23.x, A2[di].x);
                    A2[di].y = fmaf(g0f[k0o], B.o23.y, A2[di].y);
                }
            }
        }
#pragma unroll
        for (int di = 0; di < 4; ++di) {
            float2 w1 = {fmaf(SC, A1b[di].x, A1[di].x), fmaf(SC, A1b[di].y, A1[di].y)};
            float2 w2 = {SC * A2[di].x, SC * A2[di].y};
            *(float2*)&sY1[4 * qq + di][2 * u] = w1;
            *(float2*)&sY2[4 * qq + di][2 * u] = w2;
        }
    }
    __syncthreads();

    // ---- row stage: 2 quads per thread
    float* op = out + (size_t)nc * r * c;
#pragma unroll
    for (int v = 0; v < 2; ++v) {
        int lin = v * 256 + tid;
        int uq = lin & (W / 2 - 1);     // quad within row
        int il = lin >> (LOGW - 1);
        float e1[6], o1[6], e2[6], o2[6];
#pragma unroll
        for (int m = 0; m < 6; ++m) {
            int t = 2 * uq - 2 + m;
            bool sw; int tp = pairRefl(t, W, sw);
            float2 f1 = *(const float2*)&sY1[il][2 * tp];
            float2 f2 = *(const float2*)&sY2[il][2 * tp];
            e1[m] = sw ? f1.y : f1.x;  o1[m] = sw ? f1.x : f1.y;
            e2[m] = sw ? f2.y : f2.x;  o2[m] = sw ? f2.x : f2.y;
        }
        float acc[4];
#pragma unroll
        for (int s = 0; s < 4; ++s) {
            float a = 0.f;
#pragma unroll
            for (int k = 0; k < 7; ++k) {
                int rel = s + k + 1;
                int m = rel >> 1;
                a = fmaf(g0f[k], (rel & 1) ? o1[m] : e1[m], a);
            }
#pragma unroll
            for (int k = 0; k < 5; ++k) {
                int rel = s + k + 2;
                int m = rel >> 1;
                a = fmaf(g1f[k], (rel & 1) ? o2[m] : e2[m], a);
            }
            acc[s] = a;
        }
        int grow = 4 * qi0 + il;
        *(float4*)(op + (size_t)grow * c + 4 * uq) =
            make_float4(acc[0], acc[1], acc[2], acc[3]);
    }
}

extern "C" void kernel_launch(void* const* d_in, const int* in_sizes, int n_in,
                              void* d_out, int out_size, void* d_ws, size_t ws_size,
                              hipStream_t stream) {
    const float* yl  = (const float*)d_in[0];
    const float* yh1 = (const float*)d_in[1];
    const float* yh2 = (const float*)d_in[2];
    const float* yh3 = (const float*)d_in[3];
    const float* g0o = (const float*)d_in[4];
    const float* g1o = (const float*)d_in[5];
    const float* g0b = (const float*)d_in[7];
    const float* g1a = (const float*)d_in[8];
    float* out = (float*)d_out;

    const int NC = 256;
    char* ws = (char*)d_ws;
    float* llA = (float*)ws;                          // (NC,128,128) 16MB
    float* llB = (float*)(ws + ((size_t)16 << 20));   // (NC,256,256) 64MB

    // Level 3: yl + yh3 -> llA. Tile 32 rows x 128 cols (full width).
    j2_fused<32, 32><<<dim3(4, NC), 256, 0, stream>>>(yl, yh3, g0b, g1a, llA);
    // Level 2: llA + yh2 -> llB. Tile 16 rows x 256 cols.
    j2_fused<64, 64><<<dim3(16, NC), 256, 0, stream>>>(llA, yh2, g0b, g1a, llB);
    // Level 1: llB + yh1 -> out. Tile 8 rows x 256 cols.
    j1_fused<128, 128><<<dim3(32, NC), 256, 0, stream>>>(llB, yh1, g0o, g1o, out);
}

// Round 5
// 117.531 us; speedup vs baseline: 9.4212x; 1.1062x over previous
//
#include <hip/hip_runtime.h>

#define SC 0.70710678118654752440f

// branchless half-sample reflection in [0, n)
__device__ __forceinline__ int reflFull(int p, int n) {
    int x = max(p, ~p);
    return min(x, 2 * n - 1 - x);
}

// pair-space reflection: NP pairs; reflected pair index + swap flag
__device__ __forceinline__ int pairRefl(int t, int NP, bool& sw) {
    int x = max(t, ~t);
    int tp = min(x, 2 * NP - 1 - x);
    sw = (tp != t);
    return tp;
}

// coefficient index maps: cfl[s][k] = g0b[cflIdx], cfh[s][k] = g1a[cfhIdx]
__device__ __forceinline__ constexpr int cflIdx(int s, int k) {
    return (s == 0) ? 8 - 2 * k : (s == 1) ? 1 + 2 * k : (s == 2) ? 9 - 2 * k : 2 * k;
}
__device__ __forceinline__ constexpr int cfhIdx(int s, int k) {
    return (s == 0) ? 1 + 2 * k : (s == 1) ? 8 - 2 * k : (s == 2) ? 2 * k : 9 - 2 * k;
}

__device__ __forceinline__ float4 f4fma(float c, float4 a, float4 acc) {
    return make_float4(fmaf(c, a.x, acc.x), fmaf(c, a.y, acc.y),
                       fmaf(c, a.z, acc.z), fmaf(c, a.w, acc.w));
}
__device__ __forceinline__ float4 f4sel(bool sw, float4 a, float4 b) {
    return sw ? a : b;
}

struct Band4 { float4 e05, o05, e23, o23, e14, o14; };

// load 6 band float4s (2 complex = 4 output cols) at pair-row offset; produce
// even/odd-row-slot c2q values (unscaled by SC); sw swaps even/odd slots
__device__ __forceinline__ Band4 loadBands4(const float* __restrict__ bp, int HW2,
                                            int boff, bool sw) {
    float4 B0 = *(const float4*)(bp + 0 * HW2 + boff);
    float4 B1 = *(const float4*)(bp + 1 * HW2 + boff);
    float4 B2 = *(const float4*)(bp + 2 * HW2 + boff);
    float4 B3 = *(const float4*)(bp + 3 * HW2 + boff);
    float4 B4 = *(const float4*)(bp + 4 * HW2 + boff);
    float4 B5 = *(const float4*)(bp + 5 * HW2 + boff);
    float4 ve05 = {B0.x + B5.x, B0.y + B5.y, B0.z + B5.z, B0.w + B5.w};
    float4 vo05 = {B0.y - B5.y, B5.x - B0.x, B0.w - B5.w, B5.z - B0.z};
    float4 ve23 = {B2.x + B3.x, B2.y + B3.y, B2.z + B3.z, B2.w + B3.w};
    float4 vo23 = {B2.y - B3.y, B3.x - B2.x, B2.w - B3.w, B3.z - B2.z};
    float4 ve14 = {B1.x + B4.x, B1.y + B4.y, B1.z + B4.z, B1.w + B4.w};
    float4 vo14 = {B1.y - B4.y, B4.x - B1.x, B1.w - B4.w, B4.z - B1.z};
    Band4 r;
    r.e05 = f4sel(sw, vo05, ve05);  r.o05 = f4sel(sw, ve05, vo05);
    r.e23 = f4sel(sw, vo23, ve23);  r.o23 = f4sel(sw, ve23, vo23);
    r.e14 = f4sel(sw, vo14, ve14);  r.o14 = f4sel(sw, ve14, vo14);
    return r;
}

template <int N> struct Log2 { static constexpr int v = 1 + Log2<N / 2>::v; };
template <> struct Log2<1> { static constexpr int v = 0; };

// ---------------------------------------------------------------------------
// Fused j2 level: ll (nc,2H,2W) + yh (nc,6,H,W,2) -> out (nc,4H,4W)
// Col stage: 256 tasks (qq,u4), each = 4 rows x 4 cols (float4) -> LDS.
// Row stage: full-width, pairRefl resolves inside LDS.
// ---------------------------------------------------------------------------
template <int H, int W>
__global__ __launch_bounds__(256) void j2_fused(
        const float* __restrict__ ll, const float* __restrict__ yh,
        const float* __restrict__ g0b, const float* __restrict__ g1a,
        float* __restrict__ out) {
    constexpr int LOGW = Log2<W>::v;
    constexpr int U4 = W / 2, LOGU4 = LOGW - 1;
    constexpr int QI = 256 / U4;         // quad-rows per tile
    constexpr int TI = 4 * QI;           // tile rows
    constexpr int r = 2 * H, C2 = 2 * W, COUT = 4 * W, LOGC2 = LOGW + 1;
    constexpr int HW2 = H * W * 2;
    __shared__ float sY1[TI][C2];
    __shared__ float sY2[TI][C2];

    const int tid = threadIdx.x;
    const int nc = blockIdx.y;
    const int q0 = blockIdx.x * QI;
    const float* llp = ll + (size_t)nc * r * C2;
    const float* bp  = yh + (size_t)nc * 6 * HW2;

    float G0[10], G1[10];
#pragma unroll
    for (int i = 0; i < 10; ++i) { G0[i] = g0b[i]; G1[i] = g1a[i]; }

    // ---- col stage
    {
        int u4 = tid & (U4 - 1);
        int qq = tid >> LOGU4;
        int q = q0 + qq;
        float4 A1[4], A1b[4], A2[4];
#pragma unroll
        for (int s = 0; s < 4; ++s) {
            A1[s] = {0, 0, 0, 0}; A1b[s] = {0, 0, 0, 0}; A2[s] = {0, 0, 0, 0};
        }
#pragma unroll
        for (int k = 0; k < 5; ++k) {
            int t = q + k - 2;
            int pe = reflFull(2 * t, r);
            int po = reflFull(2 * t + 1, r);
            float4 lle = *(const float4*)(llp + ((pe << LOGC2) + 4 * u4));
            float4 llo = *(const float4*)(llp + ((po << LOGC2) + 4 * u4));
            bool sw; int tp = pairRefl(t, H, sw);
            int boff = (tp << (LOGW + 1)) + 4 * u4;
            Band4 B = loadBands4(bp, HW2, boff, sw);
#pragma unroll
            for (int s = 0; s < 4; ++s) {
                float4 lv  = (s & 1) ? llo   : lle;
                float4 v05 = (s & 1) ? B.e05 : B.o05;
                float4 v23 = (s & 1) ? B.o23 : B.e23;
                float4 v14 = (s & 1) ? B.e14 : B.o14;
                float c0 = G0[cflIdx(s, k)];
                float c1 = G1[cfhIdx(s, k)];
                A1[s]  = f4fma(c0, lv,  A1[s]);
                A1b[s] = f4fma(c1, v05, A1b[s]);
                A2[s]  = f4fma(c0, v23, f4fma(c1, v14, A2[s]));
            }
        }
#pragma unroll
        for (int s = 0; s < 4; ++s) {
            float4 w1 = f4fma(SC, A1b[s], A1[s]);
            float4 w2 = {SC * A2[s].x, SC * A2[s].y, SC * A2[s].z, SC * A2[s].w};
            *(float4*)&sY1[4 * qq + s][4 * u4] = w1;
            *(float4*)&sY2[4 * qq + s][4 * u4] = w2;
        }
    }
    __syncthreads();

    // ---- row stage
    float* op = out + (size_t)nc * (4 * H) * COUT;
#pragma unroll
    for (int v = 0; v < (TI * W) / 256; ++v) {
        int lin = v * 256 + tid;
        int qc = lin & (W - 1);
        int il = lin >> LOGW;
        float e1[5], o1[5], e2[5], o2[5];
#pragma unroll
        for (int m = 0; m < 5; ++m) {
            int t = qc + m - 2;
            bool sw; int tp = pairRefl(t, W, sw);
            float2 f1 = *(const float2*)&sY1[il][2 * tp];
            float2 f2 = *(const float2*)&sY2[il][2 * tp];
            e1[m] = sw ? f1.y : f1.x;  o1[m] = sw ? f1.x : f1.y;
            e2[m] = sw ? f2.y : f2.x;  o2[m] = sw ? f2.x : f2.y;
        }
        float acc[4];
#pragma unroll
        for (int s = 0; s < 4; ++s) {
            float a = 0.f;
#pragma unroll
            for (int k = 0; k < 5; ++k) {
                float v1 = (s & 1) ? o1[k] : e1[k];
                float v2 = (s & 1) ? e2[k] : o2[k];
                a = fmaf(G0[cflIdx(s, k)], v1, a);
                a = fmaf(G1[cfhIdx(s, k)], v2, a);
            }
            acc[s] = a;
        }
        int grow = 4 * q0 + il;
        *(float4*)(op + (size_t)grow * COUT + 4 * qc) =
            make_float4(acc[0], acc[1], acc[2], acc[3]);
    }
}

// ---------------------------------------------------------------------------
// Fused j1: ll (nc,r,c) + yh (nc,6,H,W,2) -> out (nc,r,c), r=2H, c=2W
// Col stage: 256 tasks (qq,u4) = 4 rows x 4 cols; row stage full-width.
// ---------------------------------------------------------------------------
template <int H, int W>
__global__ __launch_bounds__(256) void j1_fused(
        const float* __restrict__ ll, const float* __restrict__ yh,
        const float* __restrict__ g0o, const float* __restrict__ g1o,
        float* __restrict__ out) {
    constexpr int LOGW = Log2<W>::v;
    constexpr int U4 = W / 2, LOGU4 = LOGW - 1;
    constexpr int QI = 256 / U4;         // quad-row groups per tile
    constexpr int TI = 4 * QI;           // tile rows
    constexpr int r = 2 * H, c = 2 * W, LOGC2 = LOGW + 1;
    constexpr int HW2 = H * W * 2;
    __shared__ float sY1[TI][c];
    __shared__ float sY2[TI][c];

    const int tid = threadIdx.x;
    const int nc = blockIdx.y;
    const int qi0 = blockIdx.x * QI;
    const float* llp = ll + (size_t)nc * r * c;
    const float* bp  = yh + (size_t)nc * 6 * HW2;

    float g0f[7], g1f[5];
#pragma unroll
    for (int k = 0; k < 7; ++k) g0f[k] = g0o[6 - k];
#pragma unroll
    for (int k = 0; k < 5; ++k) g1f[k] = g1o[4 - k];

    // ---- col stage
    {
        int u4 = tid & (U4 - 1);
        int qq = tid >> LOGU4;
        int qi = qi0 + qq;
        float4 A1[4], A1b[4], A2[4];
#pragma unroll
        for (int s = 0; s < 4; ++s) {
            A1[s] = {0, 0, 0, 0}; A1b[s] = {0, 0, 0, 0}; A2[s] = {0, 0, 0, 0};
        }
        // ll contribution (g0, rows 4qi-3 .. 4qi+6)
#pragma unroll
        for (int rr = 0; rr < 10; ++rr) {
            int p = reflFull(4 * qi - 3 + rr, r);
            float4 v = *(const float4*)(llp + ((p << LOGC2) + 4 * u4));
#pragma unroll
            for (int di = 0; di < 4; ++di) {
                int k = rr - di;
                if (k >= 0 && k <= 6) A1[di] = f4fma(g0f[k], v, A1[di]);
            }
        }
        // band contributions (pair rows 2qi-2 .. 2qi+3)
#pragma unroll
        for (int tr = 0; tr < 6; ++tr) {
            int t = 2 * qi - 2 + tr;
            bool sw; int tp = pairRefl(t, H, sw);
            int boff = (tp << (LOGW + 1)) + 4 * u4;
            Band4 B = loadBands4(bp, HW2, boff, sw);
#pragma unroll
            for (int di = 0; di < 4; ++di) {
                int k1e = 2 * tr - di - 2;
                int k1o = k1e + 1;
                int k0e = 2 * tr - di - 1;
                int k0o = k0e + 1;
                if (k1e >= 0 && k1e <= 4) {
                    A1b[di] = f4fma(g1f[k1e], B.e05, A1b[di]);
                    A2[di]  = f4fma(g1f[k1e], B.e14, A2[di]);
                }
                if (k1o >= 0 && k1o <= 4) {
                    A1b[di] = f4fma(g1f[k1o], B.o05, A1b[di]);
                    A2[di]  = f4fma(g1f[k1o], B.o14, A2[di]);
                }
                if (k0e >= 0 && k0e <= 6) A2[di] = f4fma(g0f[k0e], B.e23, A2[di]);
                if (k0o >= 0 && k0o <= 6) A2[di] = f4fma(g0f[k0o], B.o23, A2[di]);
            }
        }
#pragma unroll
        for (int di = 0; di < 4; ++di) {
            float4 w1 = f4fma(SC, A1b[di], A1[di]);
            float4 w2 = {SC * A2[di].x, SC * A2[di].y, SC * A2[di].z, SC * A2[di].w};
            *(float4*)&sY1[4 * qq + di][4 * u4] = w1;
            *(float4*)&sY2[4 * qq + di][4 * u4] = w2;
        }
    }
    __syncthreads();

    // ---- row stage
    float* op = out + (size_t)nc * r * c;
#pragma unroll
    for (int v = 0; v < (TI * (W / 2)) / 256; ++v) {
        int lin = v * 256 + tid;
        int uq = lin & (W / 2 - 1);
        int il = lin >> (LOGW - 1);
        float e1[6], o1[6], e2[6], o2[6];
#pragma unroll
        for (int m = 0; m < 6; ++m) {
            int t = 2 * uq - 2 + m;
            bool sw; int tp = pairRefl(t, W, sw);
            float2 f1 = *(const float2*)&sY1[il][2 * tp];
            float2 f2 = *(const float2*)&sY2[il][2 * tp];
            e1[m] = sw ? f1.y : f1.x;  o1[m] = sw ? f1.x : f1.y;
            e2[m] = sw ? f2.y : f2.x;  o2[m] = sw ? f2.x : f2.y;
        }
        float acc[4];
#pragma unroll
        for (int s = 0; s < 4; ++s) {
            float a = 0.f;
#pragma unroll
            for (int k = 0; k < 7; ++k) {
                int rel = s + k + 1;
                int m = rel >> 1;
                a = fmaf(g0f[k], (rel & 1) ? o1[m] : e1[m], a);
            }
#pragma unroll
            for (int k = 0; k < 5; ++k) {
                int rel = s + k + 2;
                int m = rel >> 1;
                a = fmaf(g1f[k], (rel & 1) ? o2[m] : e2[m], a);
            }
            acc[s] = a;
        }
        int grow = 4 * qi0 + il;
        *(float4*)(op + (size_t)grow * c + 4 * uq) =
            make_float4(acc[0], acc[1], acc[2], acc[3]);
    }
}

extern "C" void kernel_launch(void* const* d_in, const int* in_sizes, int n_in,
                              void* d_out, int out_size, void* d_ws, size_t ws_size,
                              hipStream_t stream) {
    const float* yl  = (const float*)d_in[0];
    const float* yh1 = (const float*)d_in[1];
    const float* yh2 = (const float*)d_in[2];
    const float* yh3 = (const float*)d_in[3];
    const float* g0o = (const float*)d_in[4];
    const float* g1o = (const float*)d_in[5];
    const float* g0b = (const float*)d_in[7];
    const float* g1a = (const float*)d_in[8];
    float* out = (float*)d_out;

    const int NC = 256;
    char* ws = (char*)d_ws;
    float* llA = (float*)ws;                          // (NC,128,128) 16MB
    float* llB = (float*)(ws + ((size_t)16 << 20));   // (NC,256,256) 64MB

    // Level 3: yl + yh3 -> llA. QI=16 quad-rows/block -> grid.x = 32/16 = 2.
    j2_fused<32, 32><<<dim3(2, NC), 256, 0, stream>>>(yl, yh3, g0b, g1a, llA);
    // Level 2: llA + yh2 -> llB. QI=8 -> grid.x = 64/8 = 8.
    j2_fused<64, 64><<<dim3(8, NC), 256, 0, stream>>>(llA, yh2, g0b, g1a, llB);
    // Level 1: llB + yh1 -> out. QI=4 quad-row groups -> grid.x = 64/4 = 16.
    j1_fused<128, 128><<<dim3(16, NC), 256, 0, stream>>>(llB, yh1, g0o, g1o, out);
}

// Round 6
// 100.696 us; speedup vs baseline: 10.9963x; 1.1672x over previous
//
#include <hip/hip_runtime.h>

#define SC 0.70710678118654752440f

typedef _Float16 h4v __attribute__((ext_vector_type(4)));

__device__ __forceinline__ float4 ld4(const float* __restrict__ p) {
    return *(const float4*)p;
}
__device__ __forceinline__ float4 ld4(const _Float16* __restrict__ p) {
    h4v h = *(const h4v*)p;
    return make_float4((float)h[0], (float)h[1], (float)h[2], (float)h[3]);
}
__device__ __forceinline__ void st4(float* __restrict__ p, float4 v) {
    *(float4*)p = v;
}
__device__ __forceinline__ void st4(_Float16* __restrict__ p, float4 v) {
    h4v h;
    h[0] = (_Float16)v.x; h[1] = (_Float16)v.y;
    h[2] = (_Float16)v.z; h[3] = (_Float16)v.w;
    *(h4v*)p = h;
}

// branchless half-sample reflection in [0, n)
__device__ __forceinline__ int reflFull(int p, int n) {
    int x = max(p, ~p);
    return min(x, 2 * n - 1 - x);
}

// pair-space reflection: NP pairs; reflected pair index + swap flag
__device__ __forceinline__ int pairRefl(int t, int NP, bool& sw) {
    int x = max(t, ~t);
    int tp = min(x, 2 * NP - 1 - x);
    sw = (tp != t);
    return tp;
}

// coefficient index maps: cfl[s][k] = g0b[cflIdx], cfh[s][k] = g1a[cfhIdx]
__device__ __forceinline__ constexpr int cflIdx(int s, int k) {
    return (s == 0) ? 8 - 2 * k : (s == 1) ? 1 + 2 * k : (s == 2) ? 9 - 2 * k : 2 * k;
}
__device__ __forceinline__ constexpr int cfhIdx(int s, int k) {
    return (s == 0) ? 1 + 2 * k : (s == 1) ? 8 - 2 * k : (s == 2) ? 2 * k : 9 - 2 * k;
}

__device__ __forceinline__ float4 f4fma(float c, float4 a, float4 acc) {
    return make_float4(fmaf(c, a.x, acc.x), fmaf(c, a.y, acc.y),
                       fmaf(c, a.z, acc.z), fmaf(c, a.w, acc.w));
}
__device__ __forceinline__ float4 f4sel(bool sw, float4 a, float4 b) {
    return sw ? a : b;
}

struct Band4 { float4 e05, o05, e23, o23, e14, o14; };

// load 6 band float4s (2 complex = 4 output cols) at pair-row offset; produce
// even/odd-row-slot c2q values (unscaled by SC); sw swaps even/odd slots
__device__ __forceinline__ Band4 loadBands4(const float* __restrict__ bp, int HW2,
                                            int boff, bool sw) {
    float4 B0 = *(const float4*)(bp + 0 * HW2 + boff);
    float4 B1 = *(const float4*)(bp + 1 * HW2 + boff);
    float4 B2 = *(const float4*)(bp + 2 * HW2 + boff);
    float4 B3 = *(const float4*)(bp + 3 * HW2 + boff);
    float4 B4 = *(const float4*)(bp + 4 * HW2 + boff);
    float4 B5 = *(const float4*)(bp + 5 * HW2 + boff);
    float4 ve05 = {B0.x + B5.x, B0.y + B5.y, B0.z + B5.z, B0.w + B5.w};
    float4 vo05 = {B0.y - B5.y, B5.x - B0.x, B0.w - B5.w, B5.z - B0.z};
    float4 ve23 = {B2.x + B3.x, B2.y + B3.y, B2.z + B3.z, B2.w + B3.w};
    float4 vo23 = {B2.y - B3.y, B3.x - B2.x, B2.w - B3.w, B3.z - B2.z};
    float4 ve14 = {B1.x + B4.x, B1.y + B4.y, B1.z + B4.z, B1.w + B4.w};
    float4 vo14 = {B1.y - B4.y, B4.x - B1.x, B1.w - B4.w, B4.z - B1.z};
    Band4 r;
    r.e05 = f4sel(sw, vo05, ve05);  r.o05 = f4sel(sw, ve05, vo05);
    r.e23 = f4sel(sw, vo23, ve23);  r.o23 = f4sel(sw, ve23, vo23);
    r.e14 = f4sel(sw, vo14, ve14);  r.o14 = f4sel(sw, ve14, vo14);
    return r;
}

template <int N> struct Log2 { static constexpr int v = 1 + Log2<N / 2>::v; };
template <> struct Log2<1> { static constexpr int v = 0; };

// ---------------------------------------------------------------------------
// Fused j2 level: ll (nc,2H,2W) + yh (nc,6,H,W,2) -> out (nc,4H,4W)
// Col stage: 256 tasks (qq,u4), each = 4 rows x 4 cols (float4) -> LDS.
// LDS layout: sY[row][pair] = {y1e, y1o, y2e, y2o} (float4 per pair).
// Row stage: full-width, pairRefl resolves inside LDS, one b128 per tap.
// ---------------------------------------------------------------------------
template <int H, int W, typename TIn, typename TOut>
__global__ __launch_bounds__(256) void j2_fused(
        const TIn* __restrict__ ll, const float* __restrict__ yh,
        const float* __restrict__ g0b, const float* __restrict__ g1a,
        TOut* __restrict__ out) {
    constexpr int LOGW = Log2<W>::v;
    constexpr int U4 = W / 2, LOGU4 = LOGW - 1;
    constexpr int QI = 256 / U4;         // quad-rows per tile
    constexpr int TI = 4 * QI;           // tile rows
    constexpr int r = 2 * H, C2 = 2 * W, COUT = 4 * W, LOGC2 = LOGW + 1;
    constexpr int HW2 = H * W * 2;
    __shared__ float4 sY[TI][W];         // [row][pair] = {y1e,y1o,y2e,y2o}

    const int tid = threadIdx.x;
    const int nc = blockIdx.y;
    const int q0 = blockIdx.x * QI;
    const TIn* llp = ll + (size_t)nc * r * C2;
    const float* bp  = yh + (size_t)nc * 6 * HW2;

    float G0[10], G1[10];
#pragma unroll
    for (int i = 0; i < 10; ++i) { G0[i] = g0b[i]; G1[i] = g1a[i]; }

    // ---- col stage
    {
        int u4 = tid & (U4 - 1);
        int qq = tid >> LOGU4;
        int q = q0 + qq;
        float4 A1[4], A1b[4], A2[4];
#pragma unroll
        for (int s = 0; s < 4; ++s) {
            A1[s] = {0, 0, 0, 0}; A1b[s] = {0, 0, 0, 0}; A2[s] = {0, 0, 0, 0};
        }
#pragma unroll
        for (int k = 0; k < 5; ++k) {
            int t = q + k - 2;
            int pe = reflFull(2 * t, r);
            int po = reflFull(2 * t + 1, r);
            float4 lle = ld4(llp + ((pe << LOGC2) + 4 * u4));
            float4 llo = ld4(llp + ((po << LOGC2) + 4 * u4));
            bool sw; int tp = pairRefl(t, H, sw);
            int boff = (tp << (LOGW + 1)) + 4 * u4;
            Band4 B = loadBands4(bp, HW2, boff, sw);
#pragma unroll
            for (int s = 0; s < 4; ++s) {
                float4 lv  = (s & 1) ? llo   : lle;
                float4 v05 = (s & 1) ? B.e05 : B.o05;
                float4 v23 = (s & 1) ? B.o23 : B.e23;
                float4 v14 = (s & 1) ? B.e14 : B.o14;
                float c0 = G0[cflIdx(s, k)];
                float c1 = G1[cfhIdx(s, k)];
                A1[s]  = f4fma(c0, lv,  A1[s]);
                A1b[s] = f4fma(c1, v05, A1b[s]);
                A2[s]  = f4fma(c0, v23, f4fma(c1, v14, A2[s]));
            }
        }
#pragma unroll
        for (int s = 0; s < 4; ++s) {
            float4 w1 = f4fma(SC, A1b[s], A1[s]);
            float4 w2 = {SC * A2[s].x, SC * A2[s].y, SC * A2[s].z, SC * A2[s].w};
            sY[4 * qq + s][2 * u4]     = make_float4(w1.x, w1.y, w2.x, w2.y);
            sY[4 * qq + s][2 * u4 + 1] = make_float4(w1.z, w1.w, w2.z, w2.w);
        }
    }
    __syncthreads();

    // ---- row stage
    TOut* op = out + (size_t)nc * (4 * H) * COUT;
#pragma unroll
    for (int v = 0; v < (TI * W) / 256; ++v) {
        int lin = v * 256 + tid;
        int qc = lin & (W - 1);
        int il = lin >> LOGW;
        float e1[5], o1[5], e2[5], o2[5];
#pragma unroll
        for (int m = 0; m < 5; ++m) {
            int t = qc + m - 2;
            bool sw; int tp = pairRefl(t, W, sw);
            float4 F = sY[il][tp];
            e1[m] = sw ? F.y : F.x;  o1[m] = sw ? F.x : F.y;
            e2[m] = sw ? F.w : F.z;  o2[m] = sw ? F.z : F.w;
        }
        float acc[4];
#pragma unroll
        for (int s = 0; s < 4; ++s) {
            float a = 0.f;
#pragma unroll
            for (int k = 0; k < 5; ++k) {
                float v1 = (s & 1) ? o1[k] : e1[k];
                float v2 = (s & 1) ? e2[k] : o2[k];
                a = fmaf(G0[cflIdx(s, k)], v1, a);
                a = fmaf(G1[cfhIdx(s, k)], v2, a);
            }
            acc[s] = a;
        }
        int grow = 4 * q0 + il;
        st4(op + (size_t)grow * COUT + 4 * qc,
            make_float4(acc[0], acc[1], acc[2], acc[3]));
    }
}

// ---------------------------------------------------------------------------
// Fused j1: ll (nc,r,c) + yh (nc,6,H,W,2) -> out (nc,r,c), r=2H, c=2W
// Col stage: 256 tasks (qq,u4) = 4 rows x 4 cols; row stage full-width.
// ---------------------------------------------------------------------------
template <int H, int W, typename TIn>
__global__ __launch_bounds__(256) void j1_fused(
        const TIn* __restrict__ ll, const float* __restrict__ yh,
        const float* __restrict__ g0o, const float* __restrict__ g1o,
        float* __restrict__ out) {
    constexpr int LOGW = Log2<W>::v;
    constexpr int U4 = W / 2, LOGU4 = LOGW - 1;
    constexpr int QI = 256 / U4;         // quad-row groups per tile
    constexpr int TI = 4 * QI;           // tile rows
    constexpr int r = 2 * H, c = 2 * W, LOGC2 = LOGW + 1;
    constexpr int HW2 = H * W * 2;
    __shared__ float4 sY[TI][W];         // [row][pair] = {y1e,y1o,y2e,y2o}

    const int tid = threadIdx.x;
    const int nc = blockIdx.y;
    const int qi0 = blockIdx.x * QI;
    const TIn* llp = ll + (size_t)nc * r * c;
    const float* bp  = yh + (size_t)nc * 6 * HW2;

    float g0f[7], g1f[5];
#pragma unroll
    for (int k = 0; k < 7; ++k) g0f[k] = g0o[6 - k];
#pragma unroll
    for (int k = 0; k < 5; ++k) g1f[k] = g1o[4 - k];

    // ---- col stage
    {
        int u4 = tid & (U4 - 1);
        int qq = tid >> LOGU4;
        int qi = qi0 + qq;
        float4 A1[4], A1b[4], A2[4];
#pragma unroll
        for (int s = 0; s < 4; ++s) {
            A1[s] = {0, 0, 0, 0}; A1b[s] = {0, 0, 0, 0}; A2[s] = {0, 0, 0, 0};
        }
        // ll contribution (g0, rows 4qi-3 .. 4qi+6)
#pragma unroll
        for (int rr = 0; rr < 10; ++rr) {
            int p = reflFull(4 * qi - 3 + rr, r);
            float4 v = ld4(llp + ((p << LOGC2) + 4 * u4));
#pragma unroll
            for (int di = 0; di < 4; ++di) {
                int k = rr - di;
                if (k >= 0 && k <= 6) A1[di] = f4fma(g0f[k], v, A1[di]);
            }
        }
        // band contributions (pair rows 2qi-2 .. 2qi+3)
#pragma unroll
        for (int tr = 0; tr < 6; ++tr) {
            int t = 2 * qi - 2 + tr;
            bool sw; int tp = pairRefl(t, H, sw);
            int boff = (tp << (LOGW + 1)) + 4 * u4;
            Band4 B = loadBands4(bp, HW2, boff, sw);
#pragma unroll
            for (int di = 0; di < 4; ++di) {
                int k1e = 2 * tr - di - 2;
                int k1o = k1e + 1;
                int k0e = 2 * tr - di - 1;
                int k0o = k0e + 1;
                if (k1e >= 0 && k1e <= 4) {
                    A1b[di] = f4fma(g1f[k1e], B.e05, A1b[di]);
                    A2[di]  = f4fma(g1f[k1e], B.e14, A2[di]);
                }
                if (k1o >= 0 && k1o <= 4) {
                    A1b[di] = f4fma(g1f[k1o], B.o05, A1b[di]);
                    A2[di]  = f4fma(g1f[k1o], B.o14, A2[di]);
                }
                if (k0e >= 0 && k0e <= 6) A2[di] = f4fma(g0f[k0e], B.e23, A2[di]);
                if (k0o >= 0 && k0o <= 6) A2[di] = f4fma(g0f[k0o], B.o23, A2[di]);
            }
        }
#pragma unroll
        for (int di = 0; di < 4; ++di) {
            float4 w1 = f4fma(SC, A1b[di], A1[di]);
            float4 w2 = {SC * A2[di].x, SC * A2[di].y, SC * A2[di].z, SC * A2[di].w};
            sY[4 * qq + di][2 * u4]     = make_float4(w1.x, w1.y, w2.x, w2.y);
            sY[4 * qq + di][2 * u4 + 1] = make_float4(w1.z, w1.w, w2.z, w2.w);
        }
    }
    __syncthreads();

    // ---- row stage
    float* op = out + (size_t)nc * r * c;
#pragma unroll
    for (int v = 0; v < (TI * (W / 2)) / 256; ++v) {
        int lin = v * 256 + tid;
        int uq = lin & (W / 2 - 1);
        int il = lin >> (LOGW - 1);
        float e1[6], o1[6], e2[6], o2[6];
#pragma unroll
        for (int m = 0; m < 6; ++m) {
            int t = 2 * uq - 2 + m;
            bool sw; int tp = pairRefl(t, W, sw);
            float4 F = sY[il][tp];
            e1[m] = sw ? F.y : F.x;  o1[m] = sw ? F.x : F.y;
            e2[m] = sw ? F.w : F.z;  o2[m] = sw ? F.z : F.w;
        }
        float acc[4];
#pragma unroll
        for (int s = 0; s < 4; ++s) {
            float a = 0.f;
#pragma unroll
            for (int k = 0; k < 7; ++k) {
                int rel = s + k + 1;
                int m = rel >> 1;
                a = fmaf(g0f[k], (rel & 1) ? o1[m] : e1[m], a);
            }
#pragma unroll
            for (int k = 0; k < 5; ++k) {
                int rel = s + k + 2;
                int m = rel >> 1;
                a = fmaf(g1f[k], (rel & 1) ? o2[m] : e2[m], a);
            }
            acc[s] = a;
        }
        int grow = 4 * qi0 + il;
        *(float4*)(op + (size_t)grow * c + 4 * uq) =
            make_float4(acc[0], acc[1], acc[2], acc[3]);
    }
}

extern "C" void kernel_launch(void* const* d_in, const int* in_sizes, int n_in,
                              void* d_out, int out_size, void* d_ws, size_t ws_size,
                              hipStream_t stream) {
    const float* yl  = (const float*)d_in[0];
    const float* yh1 = (const float*)d_in[1];
    const float* yh2 = (const float*)d_in[2];
    const float* yh3 = (const float*)d_in[3];
    const float* g0o = (const float*)d_in[4];
    const float* g1o = (const float*)d_in[5];
    const float* g0b = (const float*)d_in[7];
    const float* g1a = (const float*)d_in[8];
    float* out = (float*)d_out;

    const int NC = 256;
    char* ws = (char*)d_ws;
    _Float16* llA = (_Float16*)ws;                        // (NC,128,128) fp16, 8MB
    _Float16* llB = (_Float16*)(ws + ((size_t)16 << 20)); // (NC,256,256) fp16, 32MB

    // Level 3: yl (fp32) + yh3 -> llA (fp16). TI=64 -> grid.x = 128/64 = 2.
    j2_fused<32, 32, float, _Float16><<<dim3(2, NC), 256, 0, stream>>>(
        yl, yh3, g0b, g1a, llA);
    // Level 2: llA (fp16) + yh2 -> llB (fp16). TI=32 -> grid.x = 256/32 = 8.
    j2_fused<64, 64, _Float16, _Float16><<<dim3(8, NC), 256, 0, stream>>>(
        llA, yh2, g0b, g1a, llB);
    // Level 1: llB (fp16) + yh1 -> out (fp32). TI=16 -> grid.x = 256/16 = 16.
    j1_fused<128, 128, _Float16><<<dim3(16, NC), 256, 0, stream>>>(
        llB, yh1, g0o, g1o, out);
}